// Round 8
// baseline (259.815 us; speedup 1.0000x reference)
//
#include <hip/hip_runtime.h>

// Fused causal attention head: B=4, T=4096, D=384, K=64.
// All operands FRAGMENT-LINEAR for 32x32x16 MFMA: frag = [lane(64)][j(8)] u16 (1KB),
// index: lane&31 = m/n, lane>>5 = k-half, j = k&7; ksegs of 16 k each.
// Yk/Yq: tile(b, t32) = 4 ksegs (feat 0..63)            -> 2048 u16
// Vt:    tile(b, d>>5, key>>7) = 8 ksegs (128 keys)     -> 4096 u16
// Wka/Wqa: tile(fout>>5) x 24 ksegs (fin)               -> 12288 u16 each x2
// Wvb:     tile(d>>5)    x 24 ksegs (fin)               -> 12288 u16 x12
// Softmax: fixed-base (no max) — scores/8 ~ O(1), exp2 args small, fp32-safe.
//
// R6 lesson: per-iteration __syncthreads (compiler-mandated vmcnt(0) drain)
// serializes every visit to ~5100cy regardless of structure. R7: BARRIER-FREE
// flash — each wave computes the full 128-key P for its 32 queries in-register
// (QK duplicated 4x across d-slice waves) and transposes P into PV B-frag
// layout with permlane32_swap. R7 FAILED with NaN: raw inline-asm
// v_permlane32_swap_b32 (hazard window / operand legalization bypassed).
// R8: same structure, swap via __builtin_amdgcn_permlane32_swap (T12 verified
// path; r.x = {a.lo,b.lo}, r.y = {a.hi,b.hi}).

#define BB 4
#define TT 4096
#define DD 384

#define OWKA 0
#define OWQA 24576
#define OWVB 49152
#define OYK  196608
#define OYQ  1245184
#define OVT  2293760

#define C_EXP 0.18033688011112042f  // log2(e)/8

typedef __bf16 bf16x8 __attribute__((ext_vector_type(8)));
typedef __bf16 bf16x2v __attribute__((ext_vector_type(2)));
typedef float f32x16 __attribute__((ext_vector_type(16)));
typedef unsigned short u16x4 __attribute__((ext_vector_type(4)));
typedef unsigned int u32x4 __attribute__((ext_vector_type(4)));
typedef unsigned int u32x2 __attribute__((ext_vector_type(2)));

__device__ __forceinline__ unsigned short f2bf(float f) {
  unsigned int u = __builtin_bit_cast(unsigned int, f);
  u += 0x7FFFu + ((u >> 16) & 1u);
  return (unsigned short)(u >> 16);
}

__device__ __forceinline__ bf16x8 ldb8(const unsigned short* p) {
  return *reinterpret_cast<const bf16x8*>(p);
}

// ---------------- 1. Weight convert -> frag-linear (Wk/Wq A-frag, Wv B-frag) --------
__global__ __launch_bounds__(256) void convert_w(
    const float* __restrict__ Wk, const float* __restrict__ Wq,
    const float* __restrict__ Wv, unsigned short* __restrict__ ws) {
  int g = blockIdx.x * 256 + threadIdx.x;    // 512 rows x 96 float4 = 49152
  int row = g / 96;
  int fin = (g - row * 96) * 4;
  const float* src;
  unsigned short* dstbase;
  int m;
  if (row < 64)       { src = Wk + row * 384;         dstbase = ws + OWKA; m = row; }
  else if (row < 128) { src = Wq + (row - 64) * 384;  dstbase = ws + OWQA; m = row - 64; }
  else                { src = Wv + (row - 128) * 384; dstbase = ws + OWVB; m = row - 128; }
  float4 f = *reinterpret_cast<const float4*>(src + fin);
  u16x4 o;
  o[0] = f2bf(f.x); o[1] = f2bf(f.y); o[2] = f2bf(f.z); o[3] = f2bf(f.w);
  unsigned short* dst = dstbase + (m >> 5) * 12288 + (fin >> 4) * 512
                        + ((((fin >> 3) & 1) << 5) + (m & 31)) * 8 + (fin & 7);
  *reinterpret_cast<u16x4*>(dst) = o;
}

// ---------------- 2. Fused K/Q/V projection ----------------------------------------
// Block = 64 tokens, 512 threads (8 waves). X staged once in LDS frag-linear
// (serves as B-frag for K/Q and A-frag for V). Waves 0-1: Yk/Yq; waves 2-7: V.
__global__ __launch_bounds__(512) void proj_fused(
    const float* __restrict__ x, const unsigned short* __restrict__ ws_r,
    unsigned short* __restrict__ Yk, unsigned short* __restrict__ Yq,
    unsigned short* __restrict__ Vt) {
  __shared__ __align__(16) unsigned short xlds[24576];   // [t32(2)][kseg(24)][64][8]
  int tb = blockIdx.x;                        // 0..255
  int b = tb >> 6;
  int tid = threadIdx.x;
  // stage X: row r = tid>>3 (64 rows), e = tid&7 (segment of 48 feats)
  {
    int r = tid >> 3, e = tid & 7;
    const float* xr = x + (tb * 64 + r) * DD + e * 48;
#pragma unroll
    for (int i = 0; i < 12; i++) {
      int fin = e * 48 + i * 4;
      float4 f = *reinterpret_cast<const float4*>(xr + i * 4);
      u16x4 o;
      o[0] = f2bf(f.x); o[1] = f2bf(f.y); o[2] = f2bf(f.z); o[3] = f2bf(f.w);
      unsigned short* dst = xlds + (r >> 5) * 12288 + (fin >> 4) * 512
                            + ((((fin >> 3) & 1) << 5) + (r & 31)) * 8 + (fin & 7);
      *reinterpret_cast<u16x4*>(dst) = o;
    }
  }
  __syncthreads();
  int wid = tid >> 6, lane = tid & 63;
  int l31 = lane & 31, h8 = lane >> 5;
  const f32x16 fz16 = {};
  if (wid < 2) {
    // Yk (wid 0) / Yq (wid 1): A = W[2 mtiles], B = X[2 ntiles]
    const unsigned short* Wa = ws_r + (wid ? OWQA : OWKA) + lane * 8;
    unsigned short* Ysel = (wid ? Yq : Yk);
    f32x16 acc[2][2];
    acc[0][0] = fz16; acc[0][1] = fz16; acc[1][0] = fz16; acc[1][1] = fz16;
    for (int ks = 0; ks < 24; ks++) {
      bf16x8 a0 = ldb8(Wa + ks * 512);
      bf16x8 a1 = ldb8(Wa + 12288 + ks * 512);
      bf16x8 b0 = ldb8(xlds + ks * 512 + lane * 8);
      bf16x8 b1 = ldb8(xlds + 12288 + ks * 512 + lane * 8);
      acc[0][0] = __builtin_amdgcn_mfma_f32_32x32x16_bf16(a0, b0, acc[0][0], 0, 0, 0);
      acc[0][1] = __builtin_amdgcn_mfma_f32_32x32x16_bf16(a0, b1, acc[0][1], 0, 0, 0);
      acc[1][0] = __builtin_amdgcn_mfma_f32_32x32x16_bf16(a1, b0, acc[1][0], 0, 0, 0);
      acc[1][1] = __builtin_amdgcn_mfma_f32_32x32x16_bf16(a1, b1, acc[1][1], 0, 0, 0);
    }
    // C[fout = mt*32 + rg*8+4h8+i][token = tb*64 + nt*32 + l31]
#pragma unroll
    for (int mt = 0; mt < 2; mt++)
#pragma unroll
      for (int nt = 0; nt < 2; nt++) {
        int tile = b * 128 + (tb & 63) * 2 + nt;
#pragma unroll
        for (int rg = 0; rg < 4; rg++) {
          u16x4 o;
#pragma unroll
          for (int i = 0; i < 4; i++) o[i] = f2bf(acc[mt][nt][rg * 4 + i]);
          *reinterpret_cast<u16x4*>(Ysel + tile * 2048 + (mt * 2 + (rg >> 1)) * 512
                                    + (((rg & 1) << 5) + l31) * 8 + 4 * h8) = o;
        }
      }
  } else {
    // V: A = X[2 token tiles], B = Wv[2 d-tiles]; vw in [0,6)
    int vw = wid - 2;
    const unsigned short* Wb = ws_r + OWVB + vw * 2 * 12288 + lane * 8;
    f32x16 acc[2][2];
    acc[0][0] = fz16; acc[0][1] = fz16; acc[1][0] = fz16; acc[1][1] = fz16;
    for (int ks = 0; ks < 24; ks++) {
      bf16x8 a0 = ldb8(xlds + ks * 512 + lane * 8);
      bf16x8 a1 = ldb8(xlds + 12288 + ks * 512 + lane * 8);
      bf16x8 w0 = ldb8(Wb + ks * 512);
      bf16x8 w1 = ldb8(Wb + 12288 + ks * 512);
      acc[0][0] = __builtin_amdgcn_mfma_f32_32x32x16_bf16(a0, w0, acc[0][0], 0, 0, 0);
      acc[0][1] = __builtin_amdgcn_mfma_f32_32x32x16_bf16(a0, w1, acc[0][1], 0, 0, 0);
      acc[1][0] = __builtin_amdgcn_mfma_f32_32x32x16_bf16(a1, w0, acc[1][0], 0, 0, 0);
      acc[1][1] = __builtin_amdgcn_mfma_f32_32x32x16_bf16(a1, w1, acc[1][1], 0, 0, 0);
    }
    // C[key = tb*64 + t32*32 + rg*8+4h8+i][d = vw*64 + dt*32 + l31]
    int k128 = (tb & 63) >> 1;               // key-block WITHIN batch
#pragma unroll
    for (int t32 = 0; t32 < 2; t32++)
#pragma unroll
      for (int dt = 0; dt < 2; dt++) {
        int dti = vw * 2 + dt;
        unsigned short* vbase = Vt + ((b * 12 + dti) * 32 + k128) * 4096;
#pragma unroll
        for (int rg = 0; rg < 4; rg++) {
          u16x4 o;
#pragma unroll
          for (int i = 0; i < 4; i++) o[i] = f2bf(acc[t32][dt][rg * 4 + i]);
          int kseg = 4 * (tb & 1) + t32 * 2 + (rg >> 1);
          *reinterpret_cast<u16x4*>(vbase + kseg * 512
                                    + (((rg & 1) << 5) + l31) * 8 + 4 * h8) = o;
        }
      }
  }
}

// ---------------- 3. Flash attention: barrier-free, in-register P transpose -------
// b = (blk&7)>>1: each XCD works one batch -> Vt(b)+Yk(b) ~3.6MB fits its 4MB L2.
// 8 waves/block (512 thr): wave = (g = key-parity, ds = d-slice of 96).
// Each wave: full 128-key QK for its 32 queries (A=K so C col = query = l31),
// mask+exp+pack to bf16 pairs, permlane32_swap h8-half exchange -> PV B-frags
// IN REGISTER (no LDS, no barrier in the loop). PV over its d-slice.
// QK duplicated 4x across ds waves (16 of 112 MFMA/visit); K reuse hits L1.
// kb strided by 2 over g; final combine = one LDS exchange + one __syncthreads.
__global__ __launch_bounds__(512, 2) void flash_attn(
    const unsigned short* __restrict__ Yk, const unsigned short* __restrict__ Yq,
    const unsigned short* __restrict__ Vt, float* __restrict__ out) {
  __shared__ float fb[4][3136];              // [ds][48 acc elems * 64 lanes + 64 psum]
  int blk = blockIdx.x;
  int xcd = blk & 7;
  int b = xcd >> 1, half = xcd & 1;
  int n = blk >> 3;
  int st = (n < 32) ? (127 - 2 * n - half) : (2 * (n - 32) + half);
  int tid = threadIdx.x;
  int wid = tid >> 6, lane = tid & 63;
  int g = wid >> 2, ds = wid & 3;
  int l31 = lane & 31, h8 = lane >> 5;
  const f32x16 fz16 = {};
  const unsigned short* qbase = Yq + (b * 128 + st) * 2048 + lane * 8;
  bf16x8 qf[4];
#pragma unroll
  for (int ks = 0; ks < 4; ks++) qf[ks] = ldb8(qbase + ks * 512);
  f32x16 acc[3];
  acc[0] = fz16; acc[1] = fz16; acc[2] = fz16;
  float psum = 0.f;
  int n128 = (st >> 2) + 1;
  int qrow = st * 32 + l31;
  const unsigned short* kbb = Yk + (b * 128) * 2048 + lane * 8;
  const unsigned short* vbase = Vt + ((b * 12 + ds * 3) * 32) * 4096 + lane * 8;
#pragma unroll 1
  for (int kb = g; kb < n128; kb += 2) {
    // V fragments for this wave's d-slice: independent, issue first
    const unsigned short* vt = vbase + kb * 4096;
    bf16x8 vf[3][8];
#pragma unroll
    for (int dt = 0; dt < 3; dt++)
#pragma unroll
      for (int q = 0; q < 8; q++) vf[dt][q] = ldb8(vt + dt * 131072 + q * 512);
    const unsigned short* kt0 = kbb + kb * 8192;
    bf16x8 pfr[8];
#pragma unroll
    for (int kt = 0; kt < 4; kt++) {
      bf16x8 k0 = ldb8(kt0 + kt * 2048);
      bf16x8 k1 = ldb8(kt0 + kt * 2048 + 512);
      bf16x8 k2 = ldb8(kt0 + kt * 2048 + 1024);
      bf16x8 k3 = ldb8(kt0 + kt * 2048 + 1536);
      f32x16 s = fz16;
      s = __builtin_amdgcn_mfma_f32_32x32x16_bf16(k0, qf[0], s, 0, 0, 0);
      s = __builtin_amdgcn_mfma_f32_32x32x16_bf16(k1, qf[1], s, 0, 0, 0);
      s = __builtin_amdgcn_mfma_f32_32x32x16_bf16(k2, qf[2], s, 0, 0, 0);
      s = __builtin_amdgcn_mfma_f32_32x32x16_bf16(k3, qf[3], s, 0, 0, 0);
      // s reg r = score(query l31, key kg + (r&3) + 8*(r>>2)) with kg below
      int kg = kb * 128 + kt * 32 + 4 * h8;
      unsigned int w[8];
#pragma unroll
      for (int i = 0; i < 8; i++) {
        int r0 = 2 * i;
        int key0 = kg + (r0 & 3) + 8 * (r0 >> 2);
        float p0 = (key0 > qrow) ? 0.f : exp2f(s[r0] * C_EXP);
        float p1 = (key0 + 1 > qrow) ? 0.f : exp2f(s[r0 + 1] * C_EXP);
        psum += p0 + p1;
        bf16x2v t; t[0] = (__bf16)p0; t[1] = (__bf16)p1;
        w[i] = __builtin_bit_cast(unsigned int, t);
      }
      // h8-half exchange via builtin (T12 verified): res.x = {a.lo, b.lo},
      // res.y = {a.hi, b.hi}. frag(2kt) = {r01.x, r23.x, r01.y, r23.y} etc.
      u32x2 r0 = __builtin_amdgcn_permlane32_swap(w[0], w[2], false, false);
      u32x2 r1 = __builtin_amdgcn_permlane32_swap(w[1], w[3], false, false);
      u32x2 r2 = __builtin_amdgcn_permlane32_swap(w[4], w[6], false, false);
      u32x2 r3 = __builtin_amdgcn_permlane32_swap(w[5], w[7], false, false);
      u32x4 f0; f0[0] = r0[0]; f0[1] = r1[0]; f0[2] = r0[1]; f0[3] = r1[1];
      u32x4 f1; f1[0] = r2[0]; f1[1] = r3[0]; f1[2] = r2[1]; f1[3] = r3[1];
      pfr[2 * kt] = __builtin_bit_cast(bf16x8, f0);
      pfr[2 * kt + 1] = __builtin_bit_cast(bf16x8, f1);
    }
#pragma unroll
    for (int q = 0; q < 8; q++) {
      acc[0] = __builtin_amdgcn_mfma_f32_32x32x16_bf16(vf[0][q], pfr[q], acc[0], 0, 0, 0);
      acc[1] = __builtin_amdgcn_mfma_f32_32x32x16_bf16(vf[1][q], pfr[q], acc[1], 0, 0, 0);
      acc[2] = __builtin_amdgcn_mfma_f32_32x32x16_bf16(vf[2][q], pfr[q], acc[2], 0, 0, 0);
    }
  }
  // psum: lane pair (l31, l31+32) hold complementary key halves of this g-half
  psum += __shfl_xor(psum, 32);
  // ---- single end-of-kernel combine across g ----
  if (g == 1) {
    float* f = fb[ds];
#pragma unroll
    for (int dt = 0; dt < 3; dt++)
#pragma unroll
      for (int e = 0; e < 16; e++) f[(dt * 16 + e) * 64 + lane] = acc[dt][e];
    f[3072 + lane] = psum;
  }
  __syncthreads();
  if (g == 0) {
    const float* f = fb[ds];
    float lt = psum + f[3072 + lane];
    float inv = 1.0f / lt;
    float* ob = out + (b * TT + st * 32 + l31) * DD + ds * 96;
#pragma unroll
    for (int dt = 0; dt < 3; dt++)
#pragma unroll
      for (int rg = 0; rg < 4; rg++) {
        float4 o4;
        o4.x = (acc[dt][rg * 4 + 0] + f[(dt * 16 + rg * 4 + 0) * 64 + lane]) * inv;
        o4.y = (acc[dt][rg * 4 + 1] + f[(dt * 16 + rg * 4 + 1) * 64 + lane]) * inv;
        o4.z = (acc[dt][rg * 4 + 2] + f[(dt * 16 + rg * 4 + 2) * 64 + lane]) * inv;
        o4.w = (acc[dt][rg * 4 + 3] + f[(dt * 16 + rg * 4 + 3) * 64 + lane]) * inv;
        *reinterpret_cast<float4*>(ob + dt * 32 + rg * 8 + h8 * 4) = o4;
      }
  }
}

extern "C" void kernel_launch(void* const* d_in, const int* in_sizes, int n_in,
                              void* d_out, int out_size, void* d_ws, size_t ws_size,
                              hipStream_t stream) {
  const float* x  = (const float*)d_in[0];
  const float* Wk = (const float*)d_in[1];
  const float* Wq = (const float*)d_in[2];
  const float* Wv = (const float*)d_in[3];
  unsigned short* ws = (unsigned short*)d_ws;
  unsigned short* Yk = ws + OYK;
  unsigned short* Yq = ws + OYQ;
  unsigned short* Vt = ws + OVT;

  convert_w<<<192, 256, 0, stream>>>(Wk, Wq, Wv, ws);
  proj_fused<<<256, 512, 0, stream>>>(x, ws, Yk, Yq, Vt);
  flash_attn<<<512, 512, 0, stream>>>(Yk, Yq, Vt, (float*)d_out);
}

// Round 9
// 188.429 us; speedup vs baseline: 1.3788x; 1.3788x over previous
//
#include <hip/hip_runtime.h>

// Fused causal attention head: B=4, T=4096, D=384, K=64.
// All operands FRAGMENT-LINEAR for 32x32x16 MFMA: frag = [lane(64)][j(8)] u16 (1KB),
// index: lane&31 = m/n, lane>>5 = k-half, j = k&7; ksegs of 16 k each.
// Yk/Yq: tile(b, t32) = 4 ksegs (feat 0..63)            -> 2048 u16
// Vt:    tile(b, d>>5, key>>7) = 8 ksegs (128 keys)     -> 4096 u16
// Wka/Wqa: tile(fout>>5) x 24 ksegs (fin)               -> 12288 u16 each x2
// Wvb:     tile(d>>5)    x 24 ksegs (fin)               -> 12288 u16 x12
// Softmax: fixed-base (no max) — scores/8 ~ O(1), exp2 args small, fp32-safe.
//
// R8: barrier-free flash verified correct (permlane32_swap builtin transpose,
// bank conflicts 0) but 173us: VGPR=92 shows the scheduler sank every load to
// its use -> 40 loads/visit fully serialized (~26k cy/visit), and V-before-K
// source order made QK's first use drain all 40. R9: pin the pipeline —
// (1) K loads FIRST (oldest in vmcnt queue) so QK waits at vmcnt(24) and the
// 24 V loads stay in flight under QK/exp/pack; (2) asm memory fences stop the
// scheduler sinking loads; (3) volatile identity-pin on qf[0] stops the
// register-only QK MFMAs hoisting above the V issue (they ignore mem fences).

#define BB 4
#define TT 4096
#define DD 384

#define OWKA 0
#define OWQA 24576
#define OWVB 49152
#define OYK  196608
#define OYQ  1245184
#define OVT  2293760

#define C_EXP 0.18033688011112042f  // log2(e)/8

typedef __bf16 bf16x8 __attribute__((ext_vector_type(8)));
typedef __bf16 bf16x2v __attribute__((ext_vector_type(2)));
typedef float f32x16 __attribute__((ext_vector_type(16)));
typedef unsigned short u16x4 __attribute__((ext_vector_type(4)));
typedef unsigned int u32x4 __attribute__((ext_vector_type(4)));
typedef unsigned int u32x2 __attribute__((ext_vector_type(2)));

__device__ __forceinline__ unsigned short f2bf(float f) {
  unsigned int u = __builtin_bit_cast(unsigned int, f);
  u += 0x7FFFu + ((u >> 16) & 1u);
  return (unsigned short)(u >> 16);
}

__device__ __forceinline__ bf16x8 ldb8(const unsigned short* p) {
  return *reinterpret_cast<const bf16x8*>(p);
}

// ---------------- 1. Weight convert -> frag-linear (Wk/Wq A-frag, Wv B-frag) --------
__global__ __launch_bounds__(256) void convert_w(
    const float* __restrict__ Wk, const float* __restrict__ Wq,
    const float* __restrict__ Wv, unsigned short* __restrict__ ws) {
  int g = blockIdx.x * 256 + threadIdx.x;    // 512 rows x 96 float4 = 49152
  int row = g / 96;
  int fin = (g - row * 96) * 4;
  const float* src;
  unsigned short* dstbase;
  int m;
  if (row < 64)       { src = Wk + row * 384;         dstbase = ws + OWKA; m = row; }
  else if (row < 128) { src = Wq + (row - 64) * 384;  dstbase = ws + OWQA; m = row - 64; }
  else                { src = Wv + (row - 128) * 384; dstbase = ws + OWVB; m = row - 128; }
  float4 f = *reinterpret_cast<const float4*>(src + fin);
  u16x4 o;
  o[0] = f2bf(f.x); o[1] = f2bf(f.y); o[2] = f2bf(f.z); o[3] = f2bf(f.w);
  unsigned short* dst = dstbase + (m >> 5) * 12288 + (fin >> 4) * 512
                        + ((((fin >> 3) & 1) << 5) + (m & 31)) * 8 + (fin & 7);
  *reinterpret_cast<u16x4*>(dst) = o;
}

// ---------------- 2. Fused K/Q/V projection ----------------------------------------
// Block = 64 tokens, 512 threads (8 waves). X staged once in LDS frag-linear
// (serves as B-frag for K/Q and A-frag for V). Waves 0-1: Yk/Yq; waves 2-7: V.
__global__ __launch_bounds__(512) void proj_fused(
    const float* __restrict__ x, const unsigned short* __restrict__ ws_r,
    unsigned short* __restrict__ Yk, unsigned short* __restrict__ Yq,
    unsigned short* __restrict__ Vt) {
  __shared__ __align__(16) unsigned short xlds[24576];   // [t32(2)][kseg(24)][64][8]
  int tb = blockIdx.x;                        // 0..255
  int b = tb >> 6;
  int tid = threadIdx.x;
  // stage X: row r = tid>>3 (64 rows), e = tid&7 (segment of 48 feats)
  {
    int r = tid >> 3, e = tid & 7;
    const float* xr = x + (tb * 64 + r) * DD + e * 48;
#pragma unroll
    for (int i = 0; i < 12; i++) {
      int fin = e * 48 + i * 4;
      float4 f = *reinterpret_cast<const float4*>(xr + i * 4);
      u16x4 o;
      o[0] = f2bf(f.x); o[1] = f2bf(f.y); o[2] = f2bf(f.z); o[3] = f2bf(f.w);
      unsigned short* dst = xlds + (r >> 5) * 12288 + (fin >> 4) * 512
                            + ((((fin >> 3) & 1) << 5) + (r & 31)) * 8 + (fin & 7);
      *reinterpret_cast<u16x4*>(dst) = o;
    }
  }
  __syncthreads();
  int wid = tid >> 6, lane = tid & 63;
  int l31 = lane & 31, h8 = lane >> 5;
  const f32x16 fz16 = {};
  if (wid < 2) {
    // Yk (wid 0) / Yq (wid 1): A = W[2 mtiles], B = X[2 ntiles]
    const unsigned short* Wa = ws_r + (wid ? OWQA : OWKA) + lane * 8;
    unsigned short* Ysel = (wid ? Yq : Yk);
    f32x16 acc[2][2];
    acc[0][0] = fz16; acc[0][1] = fz16; acc[1][0] = fz16; acc[1][1] = fz16;
    for (int ks = 0; ks < 24; ks++) {
      bf16x8 a0 = ldb8(Wa + ks * 512);
      bf16x8 a1 = ldb8(Wa + 12288 + ks * 512);
      bf16x8 b0 = ldb8(xlds + ks * 512 + lane * 8);
      bf16x8 b1 = ldb8(xlds + 12288 + ks * 512 + lane * 8);
      acc[0][0] = __builtin_amdgcn_mfma_f32_32x32x16_bf16(a0, b0, acc[0][0], 0, 0, 0);
      acc[0][1] = __builtin_amdgcn_mfma_f32_32x32x16_bf16(a0, b1, acc[0][1], 0, 0, 0);
      acc[1][0] = __builtin_amdgcn_mfma_f32_32x32x16_bf16(a1, b0, acc[1][0], 0, 0, 0);
      acc[1][1] = __builtin_amdgcn_mfma_f32_32x32x16_bf16(a1, b1, acc[1][1], 0, 0, 0);
    }
    // C[fout = mt*32 + rg*8+4h8+i][token = tb*64 + nt*32 + l31]
#pragma unroll
    for (int mt = 0; mt < 2; mt++)
#pragma unroll
      for (int nt = 0; nt < 2; nt++) {
        int tile = b * 128 + (tb & 63) * 2 + nt;
#pragma unroll
        for (int rg = 0; rg < 4; rg++) {
          u16x4 o;
#pragma unroll
          for (int i = 0; i < 4; i++) o[i] = f2bf(acc[mt][nt][rg * 4 + i]);
          *reinterpret_cast<u16x4*>(Ysel + tile * 2048 + (mt * 2 + (rg >> 1)) * 512
                                    + (((rg & 1) << 5) + l31) * 8 + 4 * h8) = o;
        }
      }
  } else {
    // V: A = X[2 token tiles], B = Wv[2 d-tiles]; vw in [0,6)
    int vw = wid - 2;
    const unsigned short* Wb = ws_r + OWVB + vw * 2 * 12288 + lane * 8;
    f32x16 acc[2][2];
    acc[0][0] = fz16; acc[0][1] = fz16; acc[1][0] = fz16; acc[1][1] = fz16;
    for (int ks = 0; ks < 24; ks++) {
      bf16x8 a0 = ldb8(xlds + ks * 512 + lane * 8);
      bf16x8 a1 = ldb8(xlds + 12288 + ks * 512 + lane * 8);
      bf16x8 w0 = ldb8(Wb + ks * 512);
      bf16x8 w1 = ldb8(Wb + 12288 + ks * 512);
      acc[0][0] = __builtin_amdgcn_mfma_f32_32x32x16_bf16(a0, w0, acc[0][0], 0, 0, 0);
      acc[0][1] = __builtin_amdgcn_mfma_f32_32x32x16_bf16(a0, w1, acc[0][1], 0, 0, 0);
      acc[1][0] = __builtin_amdgcn_mfma_f32_32x32x16_bf16(a1, w0, acc[1][0], 0, 0, 0);
      acc[1][1] = __builtin_amdgcn_mfma_f32_32x32x16_bf16(a1, w1, acc[1][1], 0, 0, 0);
    }
    // C[key = tb*64 + t32*32 + rg*8+4h8+i][d = vw*64 + dt*32 + l31]
    int k128 = (tb & 63) >> 1;               // key-block WITHIN batch
#pragma unroll
    for (int t32 = 0; t32 < 2; t32++)
#pragma unroll
      for (int dt = 0; dt < 2; dt++) {
        int dti = vw * 2 + dt;
        unsigned short* vbase = Vt + ((b * 12 + dti) * 32 + k128) * 4096;
#pragma unroll
        for (int rg = 0; rg < 4; rg++) {
          u16x4 o;
#pragma unroll
          for (int i = 0; i < 4; i++) o[i] = f2bf(acc[t32][dt][rg * 4 + i]);
          int kseg = 4 * (tb & 1) + t32 * 2 + (rg >> 1);
          *reinterpret_cast<u16x4*>(vbase + kseg * 512
                                    + (((rg & 1) << 5) + l31) * 8 + 4 * h8) = o;
        }
      }
  }
}

// ---------------- 3. Flash attention: barrier-free, pinned load pipeline ----------
// b = (blk&7)>>1: each XCD works one batch -> Vt(b)+Yk(b) ~3.6MB fits its 4MB L2.
// 8 waves/block (512 thr): wave = (g = key-parity, ds = d-slice of 96).
// Per visit: 16 K loads (FIRST -> oldest in vmcnt queue), fence, 24 V loads,
// fence + qf-pin, QK (waits vmcnt(24): V stays in flight under QK/exp/pack),
// permlane32_swap transpose -> PV. No barrier in the loop; one combine at end.
__global__ __launch_bounds__(512, 2) void flash_attn(
    const unsigned short* __restrict__ Yk, const unsigned short* __restrict__ Yq,
    const unsigned short* __restrict__ Vt, float* __restrict__ out) {
  __shared__ float fb[4][3136];              // [ds][48 acc elems * 64 lanes + 64 psum]
  int blk = blockIdx.x;
  int xcd = blk & 7;
  int b = xcd >> 1, half = xcd & 1;
  int n = blk >> 3;
  int st = (n < 32) ? (127 - 2 * n - half) : (2 * (n - 32) + half);
  int tid = threadIdx.x;
  int wid = tid >> 6, lane = tid & 63;
  int g = wid >> 2, ds = wid & 3;
  int l31 = lane & 31, h8 = lane >> 5;
  const f32x16 fz16 = {};
  const unsigned short* qbase = Yq + (b * 128 + st) * 2048 + lane * 8;
  bf16x8 qf[4];
#pragma unroll
  for (int ks = 0; ks < 4; ks++) qf[ks] = ldb8(qbase + ks * 512);
  f32x16 acc[3];
  acc[0] = fz16; acc[1] = fz16; acc[2] = fz16;
  float psum = 0.f;
  int n128 = (st >> 2) + 1;
  int qrow = st * 32 + l31;
  const unsigned short* kbb = Yk + (b * 128) * 2048 + lane * 8;
  const unsigned short* vbase = Vt + ((b * 12 + ds * 3) * 32) * 4096 + lane * 8;
#pragma unroll 1
  for (int kb = g; kb < n128; kb += 2) {
    const unsigned short* kt0 = kbb + kb * 8192;
    const unsigned short* vt = vbase + kb * 4096;
    // (1) K loads FIRST: oldest in the VMEM queue, so QK's use waits at
    //     vmcnt(24) and the V loads below remain in flight.
    bf16x8 kf[16];
#pragma unroll
    for (int i = 0; i < 16; i++) kf[i] = ldb8(kt0 + i * 512);
    asm volatile("" ::: "memory");           // K issue cannot sink below here
    // (2) V loads: fly under the whole QK/exp/pack phase.
    bf16x8 vf[3][8];
#pragma unroll
    for (int dt = 0; dt < 3; dt++)
#pragma unroll
      for (int q = 0; q < 8; q++) vf[dt][q] = ldb8(vt + dt * 131072 + q * 512);
    asm volatile("" ::: "memory");           // V issue cannot sink below here
    // (3) pin qf[0] below the V fence: every kt's MFMA chain is rooted in
    //     qf[0], and register-only MFMAs would otherwise hoist above the loads.
    {
      u32x4 qp = __builtin_bit_cast(u32x4, qf[0]);
      asm volatile("" : "+v"(qp));
      qf[0] = __builtin_bit_cast(bf16x8, qp);
    }
    bf16x8 pfr[8];
#pragma unroll
    for (int kt = 0; kt < 4; kt++) {
      f32x16 s = fz16;
      s = __builtin_amdgcn_mfma_f32_32x32x16_bf16(kf[4 * kt + 0], qf[0], s, 0, 0, 0);
      s = __builtin_amdgcn_mfma_f32_32x32x16_bf16(kf[4 * kt + 1], qf[1], s, 0, 0, 0);
      s = __builtin_amdgcn_mfma_f32_32x32x16_bf16(kf[4 * kt + 2], qf[2], s, 0, 0, 0);
      s = __builtin_amdgcn_mfma_f32_32x32x16_bf16(kf[4 * kt + 3], qf[3], s, 0, 0, 0);
      // s reg r = score(query l31, key kg + (r&3) + 8*(r>>2))
      int kg = kb * 128 + kt * 32 + 4 * h8;
      unsigned int w[8];
#pragma unroll
      for (int i = 0; i < 8; i++) {
        int r0 = 2 * i;
        int key0 = kg + (r0 & 3) + 8 * (r0 >> 2);
        float p0 = (key0 > qrow) ? 0.f : exp2f(s[r0] * C_EXP);
        float p1 = (key0 + 1 > qrow) ? 0.f : exp2f(s[r0 + 1] * C_EXP);
        psum += p0 + p1;
        bf16x2v t; t[0] = (__bf16)p0; t[1] = (__bf16)p1;
        w[i] = __builtin_bit_cast(unsigned int, t);
      }
      // h8-half exchange (T12 builtin): res.x = {a.lo, b.lo}, res.y = {a.hi, b.hi}
      u32x2 r0 = __builtin_amdgcn_permlane32_swap(w[0], w[2], false, false);
      u32x2 r1 = __builtin_amdgcn_permlane32_swap(w[1], w[3], false, false);
      u32x2 r2 = __builtin_amdgcn_permlane32_swap(w[4], w[6], false, false);
      u32x2 r3 = __builtin_amdgcn_permlane32_swap(w[5], w[7], false, false);
      u32x4 f0; f0[0] = r0[0]; f0[1] = r1[0]; f0[2] = r0[1]; f0[3] = r1[1];
      u32x4 f1; f1[0] = r2[0]; f1[1] = r3[0]; f1[2] = r2[1]; f1[3] = r3[1];
      pfr[2 * kt] = __builtin_bit_cast(bf16x8, f0);
      pfr[2 * kt + 1] = __builtin_bit_cast(bf16x8, f1);
    }
#pragma unroll
    for (int q = 0; q < 8; q++) {
      acc[0] = __builtin_amdgcn_mfma_f32_32x32x16_bf16(vf[0][q], pfr[q], acc[0], 0, 0, 0);
      acc[1] = __builtin_amdgcn_mfma_f32_32x32x16_bf16(vf[1][q], pfr[q], acc[1], 0, 0, 0);
      acc[2] = __builtin_amdgcn_mfma_f32_32x32x16_bf16(vf[2][q], pfr[q], acc[2], 0, 0, 0);
    }
  }
  // psum: lane pair (l31, l31+32) hold complementary key halves of this g-half
  psum += __shfl_xor(psum, 32);
  // ---- single end-of-kernel combine across g ----
  if (g == 1) {
    float* f = fb[ds];
#pragma unroll
    for (int dt = 0; dt < 3; dt++)
#pragma unroll
      for (int e = 0; e < 16; e++) f[(dt * 16 + e) * 64 + lane] = acc[dt][e];
    f[3072 + lane] = psum;
  }
  __syncthreads();
  if (g == 0) {
    const float* f = fb[ds];
    float lt = psum + f[3072 + lane];
    float inv = 1.0f / lt;
    float* ob = out + (b * TT + st * 32 + l31) * DD + ds * 96;
#pragma unroll
    for (int dt = 0; dt < 3; dt++)
#pragma unroll
      for (int rg = 0; rg < 4; rg++) {
        float4 o4;
        o4.x = (acc[dt][rg * 4 + 0] + f[(dt * 16 + rg * 4 + 0) * 64 + lane]) * inv;
        o4.y = (acc[dt][rg * 4 + 1] + f[(dt * 16 + rg * 4 + 1) * 64 + lane]) * inv;
        o4.z = (acc[dt][rg * 4 + 2] + f[(dt * 16 + rg * 4 + 2) * 64 + lane]) * inv;
        o4.w = (acc[dt][rg * 4 + 3] + f[(dt * 16 + rg * 4 + 3) * 64 + lane]) * inv;
        *reinterpret_cast<float4*>(ob + dt * 32 + rg * 8 + h8 * 4) = o4;
      }
  }
}

extern "C" void kernel_launch(void* const* d_in, const int* in_sizes, int n_in,
                              void* d_out, int out_size, void* d_ws, size_t ws_size,
                              hipStream_t stream) {
  const float* x  = (const float*)d_in[0];
  const float* Wk = (const float*)d_in[1];
  const float* Wq = (const float*)d_in[2];
  const float* Wv = (const float*)d_in[3];
  unsigned short* ws = (unsigned short*)d_ws;
  unsigned short* Yk = ws + OYK;
  unsigned short* Yq = ws + OYQ;
  unsigned short* Vt = ws + OVT;

  convert_w<<<192, 256, 0, stream>>>(Wk, Wq, Wv, ws);
  proj_fused<<<256, 512, 0, stream>>>(x, ws, Yk, Yq, Vt);
  flash_attn<<<512, 512, 0, stream>>>(Yk, Yq, Vt, (float*)d_out);
}

// Round 10
// 150.042 us; speedup vs baseline: 1.7316x; 1.2558x over previous
//
#include <hip/hip_runtime.h>

// Fused causal attention head: B=4, T=4096, D=384, K=64.
// All operands FRAGMENT-LINEAR for 32x32x16 MFMA: frag = [lane(64)][j(8)] u16 (1KB),
// index: lane&31 = m/n, lane>>5 = k-half, j = k&7; ksegs of 16 k each.
// Yk/Yq: tile(b, t32) = 4 ksegs (feat 0..63)            -> 2048 u16
// Vt:    tile(b, d>>5, key>>7) = 8 ksegs (128 keys)     -> 4096 u16
// Wka/Wqa: tile(fout>>5) x 24 ksegs (fin)               -> 12288 u16 each x2
// Wvb:     tile(d>>5)    x 24 ksegs (fin)               -> 12288 u16 x12
// Softmax: fixed-base (no max) — scores/8 ~ O(1), exp2 args small, fp32-safe.
//
// R10: flash reverted to the verified 68us R0 kernel (barrier-free arc R7-R9
// peaked at 111us — abandoned). New target: the constant ~85us of non-flash
// time (total-flash invariant across R0/R3/R6/R8/R9). proj_fused rebuilt:
// 512 blocks x 32 tokens (2 blocks/CU, 16 waves/CU vs 1x8), coalesced X
// staging (contiguous float4 per wave), 8 waves x 48 MFMA balanced.

#define BB 4
#define TT 4096
#define DD 384

#define OWKA 0
#define OWQA 24576
#define OWVB 49152
#define OYK  196608
#define OYQ  1245184
#define OVT  2293760

#define C_EXP 0.18033688011112042f  // log2(e)/8

typedef __bf16 bf16x8 __attribute__((ext_vector_type(8)));
typedef float f32x16 __attribute__((ext_vector_type(16)));
typedef unsigned short u16x4 __attribute__((ext_vector_type(4)));

__device__ __forceinline__ unsigned short f2bf(float f) {
  unsigned int u = __builtin_bit_cast(unsigned int, f);
  u += 0x7FFFu + ((u >> 16) & 1u);
  return (unsigned short)(u >> 16);
}

__device__ __forceinline__ bf16x8 ldb8(const unsigned short* p) {
  return *reinterpret_cast<const bf16x8*>(p);
}

// ---------------- 1. Weight convert -> frag-linear (Wk/Wq A-frag, Wv B-frag) --------
__global__ __launch_bounds__(256) void convert_w(
    const float* __restrict__ Wk, const float* __restrict__ Wq,
    const float* __restrict__ Wv, unsigned short* __restrict__ ws) {
  int g = blockIdx.x * 256 + threadIdx.x;    // 512 rows x 96 float4 = 49152
  int row = g / 96;
  int fin = (g - row * 96) * 4;
  const float* src;
  unsigned short* dstbase;
  int m;
  if (row < 64)       { src = Wk + row * 384;         dstbase = ws + OWKA; m = row; }
  else if (row < 128) { src = Wq + (row - 64) * 384;  dstbase = ws + OWQA; m = row - 64; }
  else                { src = Wv + (row - 128) * 384; dstbase = ws + OWVB; m = row - 128; }
  float4 f = *reinterpret_cast<const float4*>(src + fin);
  u16x4 o;
  o[0] = f2bf(f.x); o[1] = f2bf(f.y); o[2] = f2bf(f.z); o[3] = f2bf(f.w);
  unsigned short* dst = dstbase + (m >> 5) * 12288 + (fin >> 4) * 512
                        + ((((fin >> 3) & 1) << 5) + (m & 31)) * 8 + (fin & 7);
  *reinterpret_cast<u16x4*>(dst) = o;
}

// ---------------- 2. Fused K/Q/V projection (R10: 32-token blocks) -----------------
// Block = 32 tokens (one t32 tile), 512 threads (8 waves), 512 blocks = 2/CU.
// X staged once in LDS frag-linear, COALESCED: thread tid loads float4 at
// vec-index v = tid + 512*j (contiguous across the wave), r = v/96, fin = (v%96)*4.
// Waves: wid0 = Yk (2 mtiles), wid1 = Yq, wid2-7 = V (2 d-tiles each). 48 MFMA/wave.
__global__ __launch_bounds__(512) void proj_fused(
    const float* __restrict__ x, const unsigned short* __restrict__ ws_r,
    unsigned short* __restrict__ Yk, unsigned short* __restrict__ Yq,
    unsigned short* __restrict__ Vt) {
  __shared__ __align__(16) unsigned short xlds[12288];   // [kseg(24)][64][8] = 24 KB
  int tb2 = blockIdx.x;                       // 0..511 (32-token blocks)
  int b = tb2 >> 7;                           // batch
  int tt = tb2 & 127;                         // t32 index within batch
  int tid = threadIdx.x;
  // stage X: 3072 float4, coalesced; dst frag-linear
  {
    const float* xb = x + tb2 * 12288;
#pragma unroll
    for (int j = 0; j < 6; j++) {
      int v = tid + 512 * j;                  // vec index, < 3072
      int r = v / 96;                         // token row 0..31
      int fin = (v - r * 96) * 4;             // feature 0..383, mult of 4
      float4 f = *reinterpret_cast<const float4*>(xb + v * 4);
      u16x4 o;
      o[0] = f2bf(f.x); o[1] = f2bf(f.y); o[2] = f2bf(f.z); o[3] = f2bf(f.w);
      unsigned short* dst = xlds + (fin >> 4) * 512
                            + ((((fin >> 3) & 1) << 5) + r) * 8 + (fin & 7);
      *reinterpret_cast<u16x4*>(dst) = o;
    }
  }
  __syncthreads();
  int wid = tid >> 6, lane = tid & 63;
  int l31 = lane & 31, h8 = lane >> 5;
  const f32x16 fz16 = {};
  if (wid < 2) {
    // Yk (wid 0) / Yq (wid 1): A = W[2 mtiles], B = X[1 ntile]
    const unsigned short* Wa = ws_r + (wid ? OWQA : OWKA) + lane * 8;
    unsigned short* Ysel = (wid ? Yq : Yk);
    f32x16 acc[2];
    acc[0] = fz16; acc[1] = fz16;
    for (int ks = 0; ks < 24; ks++) {
      bf16x8 a0 = ldb8(Wa + ks * 512);
      bf16x8 a1 = ldb8(Wa + 12288 + ks * 512);
      bf16x8 b0 = ldb8(xlds + ks * 512 + lane * 8);
      acc[0] = __builtin_amdgcn_mfma_f32_32x32x16_bf16(a0, b0, acc[0], 0, 0, 0);
      acc[1] = __builtin_amdgcn_mfma_f32_32x32x16_bf16(a1, b0, acc[1], 0, 0, 0);
    }
    // C[fout = mt*32 + rg*8+4h8+i][token = tb2*32 + l31]; tile = b*128 + tt
    int tile = b * 128 + tt;
#pragma unroll
    for (int mt = 0; mt < 2; mt++)
#pragma unroll
      for (int rg = 0; rg < 4; rg++) {
        u16x4 o;
#pragma unroll
        for (int i = 0; i < 4; i++) o[i] = f2bf(acc[mt][rg * 4 + i]);
        *reinterpret_cast<u16x4*>(Ysel + tile * 2048 + (mt * 2 + (rg >> 1)) * 512
                                  + (((rg & 1) << 5) + l31) * 8 + 4 * h8) = o;
      }
  } else {
    // V: A = X[1 token tile], B = Wv[2 d-tiles]; vw in [0,6)
    int vw = wid - 2;
    const unsigned short* Wb = ws_r + OWVB + vw * 2 * 12288 + lane * 8;
    f32x16 acc[2];
    acc[0] = fz16; acc[1] = fz16;
    for (int ks = 0; ks < 24; ks++) {
      bf16x8 a0 = ldb8(xlds + ks * 512 + lane * 8);
      bf16x8 w0 = ldb8(Wb + ks * 512);
      bf16x8 w1 = ldb8(Wb + 12288 + ks * 512);
      acc[0] = __builtin_amdgcn_mfma_f32_32x32x16_bf16(a0, w0, acc[0], 0, 0, 0);
      acc[1] = __builtin_amdgcn_mfma_f32_32x32x16_bf16(a0, w1, acc[1], 0, 0, 0);
    }
    // C[key = tb2*32 + rg*8+4h8+i][d = (vw*2+dt)*32 + l31]
    int k128 = tt >> 2;                       // key-block within batch
    int ks0 = (tb2 & 3) * 2;                  // kseg base within 128-key tile
#pragma unroll
    for (int dt = 0; dt < 2; dt++) {
      int dti = vw * 2 + dt;
      unsigned short* vbase = Vt + ((b * 12 + dti) * 32 + k128) * 4096;
#pragma unroll
      for (int rg = 0; rg < 4; rg++) {
        u16x4 o;
#pragma unroll
        for (int i = 0; i < 4; i++) o[i] = f2bf(acc[dt][rg * 4 + i]);
        int kseg = ks0 + (rg >> 1);
        *reinterpret_cast<u16x4*>(vbase + kseg * 512
                                  + (((rg & 1) << 5) + l31) * 8 + 4 * h8) = o;
      }
    }
  }
}

// ---------------- 3. Flash attention: cooperative 128-key iters, XCD-pinned --------
// (verified R0 kernel, 68us) b = (blk&7)>>1: each XCD works one batch.
__global__ __launch_bounds__(256, 2) void flash_attn(
    const unsigned short* __restrict__ Yk, const unsigned short* __restrict__ Yq,
    const unsigned short* __restrict__ Vt, float* __restrict__ out) {
  __shared__ __align__(16) unsigned short pbuf[2][8192];  // [kseg(8)][lane(64)][j(8)]
  __shared__ float lred[4][32];
  int blk = blockIdx.x;
  int xcd = blk & 7;
  int b = xcd >> 1, half = xcd & 1;
  int n = blk >> 3;
  int st = (n < 32) ? (127 - 2 * n - half) : (2 * (n - 32) + half);
  int wid = threadIdx.x >> 6, lane = threadIdx.x & 63;
  int l31 = lane & 31, h8 = lane >> 5;
  const f32x16 fz16 = {};
  const unsigned short* qbase = Yq + (b * 128 + st) * 2048 + lane * 8;
  bf16x8 qf[4];
#pragma unroll
  for (int ks = 0; ks < 4; ks++) qf[ks] = ldb8(qbase + ks * 512);
  f32x16 acc[3];
  acc[0] = fz16; acc[1] = fz16; acc[2] = fz16;
  float psum = 0.f;
  int n128 = (st >> 2) + 1;
  int qrow = st * 32 + l31;
  const unsigned short* kbase = Yk + (b * 128 + wid) * 2048 + lane * 8;
  const unsigned short* vbase = Vt + ((b * 12 + wid * 3) * 32) * 4096 + lane * 8;
#pragma unroll 1
  for (int kb = 0; kb < n128; kb++) {
    const unsigned short* kt = kbase + kb * 8192;
    bf16x8 kf[4];
#pragma unroll
    for (int ks = 0; ks < 4; ks++) kf[ks] = ldb8(kt + ks * 512);
    f32x16 sacc = fz16;
#pragma unroll
    for (int ks = 0; ks < 4; ks++)
      sacc = __builtin_amdgcn_mfma_f32_32x32x16_bf16(kf[ks], qf[ks], sacc, 0, 0, 0);
    int kg0 = kb * 128 + wid * 32 + 4 * h8;
    unsigned short* pw = pbuf[kb & 1];
#pragma unroll
    for (int rg = 0; rg < 4; rg++) {
      u16x4 o;
#pragma unroll
      for (int i = 0; i < 4; i++) {
        int key = kg0 + rg * 8 + i;
        float pv = (key > qrow) ? 0.f : exp2f(sacc[rg * 4 + i] * C_EXP);
        psum += pv;
        o[i] = f2bf(pv);
      }
      int g = wid * 2 + (rg >> 1);
      *reinterpret_cast<u16x4*>(pw + g * 512 + ((rg & 1) * 32 + l31) * 8 + 4 * h8) = o;
    }
    const unsigned short* vt = vbase + kb * 4096;
    bf16x8 vf0[8], vf1[8], vf2[8];
#pragma unroll
    for (int g = 0; g < 8; g++) vf0[g] = ldb8(vt + g * 512);
#pragma unroll
    for (int g = 0; g < 8; g++) vf1[g] = ldb8(vt + 32 * 4096 + g * 512);
#pragma unroll
    for (int g = 0; g < 8; g++) vf2[g] = ldb8(vt + 64 * 4096 + g * 512);
    __syncthreads();
    bf16x8 pf[8];
#pragma unroll
    for (int g = 0; g < 8; g++) pf[g] = ldb8(pw + g * 512 + lane * 8);
#pragma unroll
    for (int g = 0; g < 8; g++) {
      acc[0] = __builtin_amdgcn_mfma_f32_32x32x16_bf16(vf0[g], pf[g], acc[0], 0, 0, 0);
      acc[1] = __builtin_amdgcn_mfma_f32_32x32x16_bf16(vf1[g], pf[g], acc[1], 0, 0, 0);
      acc[2] = __builtin_amdgcn_mfma_f32_32x32x16_bf16(vf2[g], pf[g], acc[2], 0, 0, 0);
    }
  }
  psum += __shfl_xor(psum, 32);
  if (h8 == 0) lred[wid][l31] = psum;
  __syncthreads();
  float lt = lred[0][l31] + lred[1][l31] + lred[2][l31] + lred[3][l31];
  float inv = 1.0f / lt;
  float* ob = out + (b * TT + st * 32 + l31) * DD + wid * 96;
#pragma unroll
  for (int dt = 0; dt < 3; dt++)
#pragma unroll
    for (int rg = 0; rg < 4; rg++) {
      float4 o4;
      o4.x = acc[dt][rg * 4 + 0] * inv; o4.y = acc[dt][rg * 4 + 1] * inv;
      o4.z = acc[dt][rg * 4 + 2] * inv; o4.w = acc[dt][rg * 4 + 3] * inv;
      *reinterpret_cast<float4*>(ob + dt * 32 + rg * 8 + h8 * 4) = o4;
    }
}

extern "C" void kernel_launch(void* const* d_in, const int* in_sizes, int n_in,
                              void* d_out, int out_size, void* d_ws, size_t ws_size,
                              hipStream_t stream) {
  const float* x  = (const float*)d_in[0];
  const float* Wk = (const float*)d_in[1];
  const float* Wq = (const float*)d_in[2];
  const float* Wv = (const float*)d_in[3];
  unsigned short* ws = (unsigned short*)d_ws;
  unsigned short* Yk = ws + OYK;
  unsigned short* Yq = ws + OYQ;
  unsigned short* Vt = ws + OVT;

  convert_w<<<192, 256, 0, stream>>>(Wk, Wq, Wv, ws);
  proj_fused<<<512, 512, 0, stream>>>(x, ws, Yk, Yq, Vt);
  flash_attn<<<512, 256, 0, stream>>>(Yk, Yq, Vt, (float*)d_out);
}

// Round 11
// 149.254 us; speedup vs baseline: 1.7408x; 1.0053x over previous
//
#include <hip/hip_runtime.h>

// Fused causal attention head: B=4, T=4096, D=384, K=64.
// All operands FRAGMENT-LINEAR for 32x32x16 MFMA: frag = [lane(64)][j(8)] u16 (1KB),
// index: lane&31 = m/n, lane>>5 = k-half, j = k&7; ksegs of 16 k each.
// Yk/Yq: tile(b, t32) = 4 ksegs (feat 0..63)            -> 2048 u16
// Vt:    tile(b, d>>5, key>>7) = 8 ksegs (128 keys)     -> 4096 u16
// Wka/Wqa: tile(fout>>5) x 24 ksegs (fin)               -> 12288 u16 each x2
// Wvb:     tile(d>>5)    x 24 ksegs (fin)               -> 12288 u16 x12
// Softmax: fixed-base (no max) — scores/8 ~ O(1), exp2 args small, fp32-safe.
//
// R10 lesson: proj rebuild (coalescing+occupancy) left the ~85us non-flash
// residue untouched -> the ks loop's 24 serial {2 global loads -> 2 MFMA}
// iterations are the cost (hipcc sinks loads to uses; ~500cy exposed L2 latency
// x24, seen in R3/R8/R9). R11: chunked register double-buffer — issue 16 weight
// loads for chunk c+1 (16KB/wave in flight), asm memory fence, compute chunk c
// from registers. Live ~180 VGPR < 256 cap. flash = verified R0/R10 65us kernel.

#define BB 4
#define TT 4096
#define DD 384

#define OWKA 0
#define OWQA 24576
#define OWVB 49152
#define OYK  196608
#define OYQ  1245184
#define OVT  2293760

#define C_EXP 0.18033688011112042f  // log2(e)/8

typedef __bf16 bf16x8 __attribute__((ext_vector_type(8)));
typedef float f32x16 __attribute__((ext_vector_type(16)));
typedef unsigned short u16x4 __attribute__((ext_vector_type(4)));

__device__ __forceinline__ unsigned short f2bf(float f) {
  unsigned int u = __builtin_bit_cast(unsigned int, f);
  u += 0x7FFFu + ((u >> 16) & 1u);
  return (unsigned short)(u >> 16);
}

__device__ __forceinline__ bf16x8 ldb8(const unsigned short* p) {
  return *reinterpret_cast<const bf16x8*>(p);
}

// ---------------- 1. Weight convert -> frag-linear (Wk/Wq A-frag, Wv B-frag) --------
__global__ __launch_bounds__(256) void convert_w(
    const float* __restrict__ Wk, const float* __restrict__ Wq,
    const float* __restrict__ Wv, unsigned short* __restrict__ ws) {
  int g = blockIdx.x * 256 + threadIdx.x;    // 512 rows x 96 float4 = 49152
  int row = g / 96;
  int fin = (g - row * 96) * 4;
  const float* src;
  unsigned short* dstbase;
  int m;
  if (row < 64)       { src = Wk + row * 384;         dstbase = ws + OWKA; m = row; }
  else if (row < 128) { src = Wq + (row - 64) * 384;  dstbase = ws + OWQA; m = row - 64; }
  else                { src = Wv + (row - 128) * 384; dstbase = ws + OWVB; m = row - 128; }
  float4 f = *reinterpret_cast<const float4*>(src + fin);
  u16x4 o;
  o[0] = f2bf(f.x); o[1] = f2bf(f.y); o[2] = f2bf(f.z); o[3] = f2bf(f.w);
  unsigned short* dst = dstbase + (m >> 5) * 12288 + (fin >> 4) * 512
                        + ((((fin >> 3) & 1) << 5) + (m & 31)) * 8 + (fin & 7);
  *reinterpret_cast<u16x4*>(dst) = o;
}

// ---------------- 2. Fused K/Q/V projection (R11: chunked weight prefetch) ---------
// Block = 32 tokens (one t32 tile), 512 threads (8 waves), 512 blocks.
// X staged once in LDS frag-linear, coalesced. Waves: wid0 = Yk, wid1 = Yq,
// wid2-7 = V (2 d-tiles each). ks loop = 3 chunks x 8 ksegs: chunk c+1's 16
// weight frags issued (fence) before computing chunk c from registers.
__global__ __launch_bounds__(512) void proj_fused(
    const float* __restrict__ x, const unsigned short* __restrict__ ws_r,
    unsigned short* __restrict__ Yk, unsigned short* __restrict__ Yq,
    unsigned short* __restrict__ Vt) {
  __shared__ __align__(16) unsigned short xlds[12288];   // [kseg(24)][64][8] = 24 KB
  int tb2 = blockIdx.x;                       // 0..511 (32-token blocks)
  int b = tb2 >> 7;                           // batch
  int tt = tb2 & 127;                         // t32 index within batch
  int tid = threadIdx.x;
  // stage X: 3072 float4, coalesced; dst frag-linear
  {
    const float* xb = x + tb2 * 12288;
#pragma unroll
    for (int j = 0; j < 6; j++) {
      int v = tid + 512 * j;                  // vec index, < 3072
      int r = v / 96;                         // token row 0..31
      int fin = (v - r * 96) * 4;             // feature 0..383, mult of 4
      float4 f = *reinterpret_cast<const float4*>(xb + v * 4);
      u16x4 o;
      o[0] = f2bf(f.x); o[1] = f2bf(f.y); o[2] = f2bf(f.z); o[3] = f2bf(f.w);
      unsigned short* dst = xlds + (fin >> 4) * 512
                            + ((((fin >> 3) & 1) << 5) + r) * 8 + (fin & 7);
      *reinterpret_cast<u16x4*>(dst) = o;
    }
  }
  __syncthreads();
  int wid = tid >> 6, lane = tid & 63;
  int l31 = lane & 31, h8 = lane >> 5;
  const f32x16 fz16 = {};
  if (wid < 2) {
    // Yk (wid 0) / Yq (wid 1): A = W[2 mtiles], B = X[1 ntile]
    const unsigned short* Wa = ws_r + (wid ? OWQA : OWKA) + lane * 8;
    unsigned short* Ysel = (wid ? Yq : Yk);
    f32x16 acc0 = fz16, acc1 = fz16;
    bf16x8 cw0[8], cw1[8], nw0[8], nw1[8];
#pragma unroll
    for (int i = 0; i < 8; i++) {
      cw0[i] = ldb8(Wa + i * 512);
      cw1[i] = ldb8(Wa + 12288 + i * 512);
    }
    asm volatile("" ::: "memory");
#pragma unroll
    for (int c = 0; c < 3; c++) {
      if (c < 2) {
#pragma unroll
        for (int i = 0; i < 8; i++) {
          nw0[i] = ldb8(Wa + (c + 1) * 4096 + i * 512);
          nw1[i] = ldb8(Wa + 12288 + (c + 1) * 4096 + i * 512);
        }
        asm volatile("" ::: "memory");
      }
#pragma unroll
      for (int i = 0; i < 8; i++) {
        bf16x8 b0 = ldb8(xlds + (c * 8 + i) * 512 + lane * 8);
        acc0 = __builtin_amdgcn_mfma_f32_32x32x16_bf16(cw0[i], b0, acc0, 0, 0, 0);
        acc1 = __builtin_amdgcn_mfma_f32_32x32x16_bf16(cw1[i], b0, acc1, 0, 0, 0);
      }
      if (c < 2) {
#pragma unroll
        for (int i = 0; i < 8; i++) { cw0[i] = nw0[i]; cw1[i] = nw1[i]; }
      }
    }
    // C[fout = mt*32 + rg*8+4h8+i][token = tb2*32 + l31]; tile = b*128 + tt
    int tile = b * 128 + tt;
    f32x16 am[2] = {acc0, acc1};
#pragma unroll
    for (int mt = 0; mt < 2; mt++)
#pragma unroll
      for (int rg = 0; rg < 4; rg++) {
        u16x4 o;
#pragma unroll
        for (int i = 0; i < 4; i++) o[i] = f2bf(am[mt][rg * 4 + i]);
        *reinterpret_cast<u16x4*>(Ysel + tile * 2048 + (mt * 2 + (rg >> 1)) * 512
                                  + (((rg & 1) << 5) + l31) * 8 + 4 * h8) = o;
      }
  } else {
    // V: A = X[1 token tile], B = Wv[2 d-tiles]; vw in [0,6)
    int vw = wid - 2;
    const unsigned short* Wb = ws_r + OWVB + vw * 2 * 12288 + lane * 8;
    f32x16 acc0 = fz16, acc1 = fz16;
    bf16x8 cw0[8], cw1[8], nw0[8], nw1[8];
#pragma unroll
    for (int i = 0; i < 8; i++) {
      cw0[i] = ldb8(Wb + i * 512);
      cw1[i] = ldb8(Wb + 12288 + i * 512);
    }
    asm volatile("" ::: "memory");
#pragma unroll
    for (int c = 0; c < 3; c++) {
      if (c < 2) {
#pragma unroll
        for (int i = 0; i < 8; i++) {
          nw0[i] = ldb8(Wb + (c + 1) * 4096 + i * 512);
          nw1[i] = ldb8(Wb + 12288 + (c + 1) * 4096 + i * 512);
        }
        asm volatile("" ::: "memory");
      }
#pragma unroll
      for (int i = 0; i < 8; i++) {
        bf16x8 a0 = ldb8(xlds + (c * 8 + i) * 512 + lane * 8);
        acc0 = __builtin_amdgcn_mfma_f32_32x32x16_bf16(a0, cw0[i], acc0, 0, 0, 0);
        acc1 = __builtin_amdgcn_mfma_f32_32x32x16_bf16(a0, cw1[i], acc1, 0, 0, 0);
      }
      if (c < 2) {
#pragma unroll
        for (int i = 0; i < 8; i++) { cw0[i] = nw0[i]; cw1[i] = nw1[i]; }
      }
    }
    // C[key = tb2*32 + rg*8+4h8+i][d = (vw*2+dt)*32 + l31]
    int k128 = tt >> 2;                       // key-block within batch
    int ks0 = (tb2 & 3) * 2;                  // kseg base within 128-key tile
    f32x16 ad[2] = {acc0, acc1};
#pragma unroll
    for (int dt = 0; dt < 2; dt++) {
      int dti = vw * 2 + dt;
      unsigned short* vbase = Vt + ((b * 12 + dti) * 32 + k128) * 4096;
#pragma unroll
      for (int rg = 0; rg < 4; rg++) {
        u16x4 o;
#pragma unroll
        for (int i = 0; i < 4; i++) o[i] = f2bf(ad[dt][rg * 4 + i]);
        int kseg = ks0 + (rg >> 1);
        *reinterpret_cast<u16x4*>(vbase + kseg * 512
                                  + (((rg & 1) << 5) + l31) * 8 + 4 * h8) = o;
      }
    }
  }
}

// ---------------- 3. Flash attention: cooperative 128-key iters, XCD-pinned --------
// (verified R0/R10 kernel, 65us) b = (blk&7)>>1: each XCD works one batch.
__global__ __launch_bounds__(256, 2) void flash_attn(
    const unsigned short* __restrict__ Yk, const unsigned short* __restrict__ Yq,
    const unsigned short* __restrict__ Vt, float* __restrict__ out) {
  __shared__ __align__(16) unsigned short pbuf[2][8192];  // [kseg(8)][lane(64)][j(8)]
  __shared__ float lred[4][32];
  int blk = blockIdx.x;
  int xcd = blk & 7;
  int b = xcd >> 1, half = xcd & 1;
  int n = blk >> 3;
  int st = (n < 32) ? (127 - 2 * n - half) : (2 * (n - 32) + half);
  int wid = threadIdx.x >> 6, lane = threadIdx.x & 63;
  int l31 = lane & 31, h8 = lane >> 5;
  const f32x16 fz16 = {};
  const unsigned short* qbase = Yq + (b * 128 + st) * 2048 + lane * 8;
  bf16x8 qf[4];
#pragma unroll
  for (int ks = 0; ks < 4; ks++) qf[ks] = ldb8(qbase + ks * 512);
  f32x16 acc[3];
  acc[0] = fz16; acc[1] = fz16; acc[2] = fz16;
  float psum = 0.f;
  int n128 = (st >> 2) + 1;
  int qrow = st * 32 + l31;
  const unsigned short* kbase = Yk + (b * 128 + wid) * 2048 + lane * 8;
  const unsigned short* vbase = Vt + ((b * 12 + wid * 3) * 32) * 4096 + lane * 8;
#pragma unroll 1
  for (int kb = 0; kb < n128; kb++) {
    const unsigned short* kt = kbase + kb * 8192;
    bf16x8 kf[4];
#pragma unroll
    for (int ks = 0; ks < 4; ks++) kf[ks] = ldb8(kt + ks * 512);
    f32x16 sacc = fz16;
#pragma unroll
    for (int ks = 0; ks < 4; ks++)
      sacc = __builtin_amdgcn_mfma_f32_32x32x16_bf16(kf[ks], qf[ks], sacc, 0, 0, 0);
    int kg0 = kb * 128 + wid * 32 + 4 * h8;
    unsigned short* pw = pbuf[kb & 1];
#pragma unroll
    for (int rg = 0; rg < 4; rg++) {
      u16x4 o;
#pragma unroll
      for (int i = 0; i < 4; i++) {
        int key = kg0 + rg * 8 + i;
        float pv = (key > qrow) ? 0.f : exp2f(sacc[rg * 4 + i] * C_EXP);
        psum += pv;
        o[i] = f2bf(pv);
      }
      int g = wid * 2 + (rg >> 1);
      *reinterpret_cast<u16x4*>(pw + g * 512 + ((rg & 1) * 32 + l31) * 8 + 4 * h8) = o;
    }
    const unsigned short* vt = vbase + kb * 4096;
    bf16x8 vf0[8], vf1[8], vf2[8];
#pragma unroll
    for (int g = 0; g < 8; g++) vf0[g] = ldb8(vt + g * 512);
#pragma unroll
    for (int g = 0; g < 8; g++) vf1[g] = ldb8(vt + 32 * 4096 + g * 512);
#pragma unroll
    for (int g = 0; g < 8; g++) vf2[g] = ldb8(vt + 64 * 4096 + g * 512);
    __syncthreads();
    bf16x8 pf[8];
#pragma unroll
    for (int g = 0; g < 8; g++) pf[g] = ldb8(pw + g * 512 + lane * 8);
#pragma unroll
    for (int g = 0; g < 8; g++) {
      acc[0] = __builtin_amdgcn_mfma_f32_32x32x16_bf16(vf0[g], pf[g], acc[0], 0, 0, 0);
      acc[1] = __builtin_amdgcn_mfma_f32_32x32x16_bf16(vf1[g], pf[g], acc[1], 0, 0, 0);
      acc[2] = __builtin_amdgcn_mfma_f32_32x32x16_bf16(vf2[g], pf[g], acc[2], 0, 0, 0);
    }
  }
  psum += __shfl_xor(psum, 32);
  if (h8 == 0) lred[wid][l31] = psum;
  __syncthreads();
  float lt = lred[0][l31] + lred[1][l31] + lred[2][l31] + lred[3][l31];
  float inv = 1.0f / lt;
  float* ob = out + (b * TT + st * 32 + l31) * DD + wid * 96;
#pragma unroll
  for (int dt = 0; dt < 3; dt++)
#pragma unroll
    for (int rg = 0; rg < 4; rg++) {
      float4 o4;
      o4.x = acc[dt][rg * 4 + 0] * inv; o4.y = acc[dt][rg * 4 + 1] * inv;
      o4.z = acc[dt][rg * 4 + 2] * inv; o4.w = acc[dt][rg * 4 + 3] * inv;
      *reinterpret_cast<float4*>(ob + dt * 32 + rg * 8 + h8 * 4) = o4;
    }
}

extern "C" void kernel_launch(void* const* d_in, const int* in_sizes, int n_in,
                              void* d_out, int out_size, void* d_ws, size_t ws_size,
                              hipStream_t stream) {
  const float* x  = (const float*)d_in[0];
  const float* Wk = (const float*)d_in[1];
  const float* Wq = (const float*)d_in[2];
  const float* Wv = (const float*)d_in[3];
  unsigned short* ws = (unsigned short*)d_ws;
  unsigned short* Yk = ws + OYK;
  unsigned short* Yq = ws + OYQ;
  unsigned short* Vt = ws + OVT;

  convert_w<<<192, 256, 0, stream>>>(Wk, Wq, Wv, ws);
  proj_fused<<<512, 512, 0, stream>>>(x, ws, Yk, Yq, Vt);
  flash_attn<<<512, 256, 0, stream>>>(Yk, Yq, Vt, (float*)d_out);
}

// Round 12
// 145.510 us; speedup vs baseline: 1.7856x; 1.0257x over previous
//
#include <hip/hip_runtime.h>

// Fused causal attention head: B=4, T=4096, D=384, K=64.
// All operands FRAGMENT-LINEAR for 32x32x16 MFMA: frag = [lane(64)][j(8)] u16 (1KB),
// index: lane&31 = m/n, lane>>5 = k-half, j = k&7; ksegs of 16 k each.
// Yk/Yq: tile(b, t32) = 4 ksegs (feat 0..63)            -> 2048 u16
// Vt:    tile(b, d>>5, key>>7) = 8 ksegs (128 keys)     -> 4096 u16
// Wka/Wqa: tile(fout>>5) x 24 ksegs (fin)               -> 12288 u16 each x2
// Wvb:     tile(d>>5)    x 24 ksegs (fin)               -> 12288 u16 x12
// Softmax: fixed-base (no max) — scores/8 ~ O(1), exp2 args small, fp32-safe.
//
// R11 lesson: residue (total-flash = 85us) is invariant under proj rewrites ->
// stop chasing it; flash has 5x MFMA headroom (30 GFLOP -> 12.5us floor vs 64).
// R12: __syncthreads forces s_waitcnt vmcnt(0) before s_barrier (guide: the
// barrier-drain stall), serializing ~600cy V-load latency into every visit.
// The barrier only protects the P LDS tile -> replace with lgkmcnt(0)-only +
// raw s_barrier (m201 template). K(kb+1) prefetched after QK(kb), V(kb+1)
// after PV(kb); compiler emits counted vmcnt automatically. 2-buffer/1-barrier
// safety: pre-barrier lgkmcnt(0) also drains P-reads of kb-1 -> no WAR race.

#define BB 4
#define TT 4096
#define DD 384

#define OWKA 0
#define OWQA 24576
#define OWVB 49152
#define OYK  196608
#define OYQ  1245184
#define OVT  2293760

#define C_EXP 0.18033688011112042f  // log2(e)/8

typedef __bf16 bf16x8 __attribute__((ext_vector_type(8)));
typedef float f32x16 __attribute__((ext_vector_type(16)));
typedef unsigned short u16x4 __attribute__((ext_vector_type(4)));

__device__ __forceinline__ unsigned short f2bf(float f) {
  unsigned int u = __builtin_bit_cast(unsigned int, f);
  u += 0x7FFFu + ((u >> 16) & 1u);
  return (unsigned short)(u >> 16);
}

__device__ __forceinline__ bf16x8 ldb8(const unsigned short* p) {
  return *reinterpret_cast<const bf16x8*>(p);
}

// ---------------- 1. Weight convert -> frag-linear (Wk/Wq A-frag, Wv B-frag) --------
__global__ __launch_bounds__(256) void convert_w(
    const float* __restrict__ Wk, const float* __restrict__ Wq,
    const float* __restrict__ Wv, unsigned short* __restrict__ ws) {
  int g = blockIdx.x * 256 + threadIdx.x;    // 512 rows x 96 float4 = 49152
  int row = g / 96;
  int fin = (g - row * 96) * 4;
  const float* src;
  unsigned short* dstbase;
  int m;
  if (row < 64)       { src = Wk + row * 384;         dstbase = ws + OWKA; m = row; }
  else if (row < 128) { src = Wq + (row - 64) * 384;  dstbase = ws + OWQA; m = row - 64; }
  else                { src = Wv + (row - 128) * 384; dstbase = ws + OWVB; m = row - 128; }
  float4 f = *reinterpret_cast<const float4*>(src + fin);
  u16x4 o;
  o[0] = f2bf(f.x); o[1] = f2bf(f.y); o[2] = f2bf(f.z); o[3] = f2bf(f.w);
  unsigned short* dst = dstbase + (m >> 5) * 12288 + (fin >> 4) * 512
                        + ((((fin >> 3) & 1) << 5) + (m & 31)) * 8 + (fin & 7);
  *reinterpret_cast<u16x4*>(dst) = o;
}

// ---------------- 2. Fused K/Q/V projection (R11: chunked weight prefetch) ---------
__global__ __launch_bounds__(512) void proj_fused(
    const float* __restrict__ x, const unsigned short* __restrict__ ws_r,
    unsigned short* __restrict__ Yk, unsigned short* __restrict__ Yq,
    unsigned short* __restrict__ Vt) {
  __shared__ __align__(16) unsigned short xlds[12288];   // [kseg(24)][64][8] = 24 KB
  int tb2 = blockIdx.x;                       // 0..511 (32-token blocks)
  int b = tb2 >> 7;                           // batch
  int tt = tb2 & 127;                         // t32 index within batch
  int tid = threadIdx.x;
  {
    const float* xb = x + tb2 * 12288;
#pragma unroll
    for (int j = 0; j < 6; j++) {
      int v = tid + 512 * j;                  // vec index, < 3072
      int r = v / 96;                         // token row 0..31
      int fin = (v - r * 96) * 4;             // feature 0..383, mult of 4
      float4 f = *reinterpret_cast<const float4*>(xb + v * 4);
      u16x4 o;
      o[0] = f2bf(f.x); o[1] = f2bf(f.y); o[2] = f2bf(f.z); o[3] = f2bf(f.w);
      unsigned short* dst = xlds + (fin >> 4) * 512
                            + ((((fin >> 3) & 1) << 5) + r) * 8 + (fin & 7);
      *reinterpret_cast<u16x4*>(dst) = o;
    }
  }
  __syncthreads();
  int wid = tid >> 6, lane = tid & 63;
  int l31 = lane & 31, h8 = lane >> 5;
  const f32x16 fz16 = {};
  if (wid < 2) {
    const unsigned short* Wa = ws_r + (wid ? OWQA : OWKA) + lane * 8;
    unsigned short* Ysel = (wid ? Yq : Yk);
    f32x16 acc0 = fz16, acc1 = fz16;
    bf16x8 cw0[8], cw1[8], nw0[8], nw1[8];
#pragma unroll
    for (int i = 0; i < 8; i++) {
      cw0[i] = ldb8(Wa + i * 512);
      cw1[i] = ldb8(Wa + 12288 + i * 512);
    }
    asm volatile("" ::: "memory");
#pragma unroll
    for (int c = 0; c < 3; c++) {
      if (c < 2) {
#pragma unroll
        for (int i = 0; i < 8; i++) {
          nw0[i] = ldb8(Wa + (c + 1) * 4096 + i * 512);
          nw1[i] = ldb8(Wa + 12288 + (c + 1) * 4096 + i * 512);
        }
        asm volatile("" ::: "memory");
      }
#pragma unroll
      for (int i = 0; i < 8; i++) {
        bf16x8 b0 = ldb8(xlds + (c * 8 + i) * 512 + lane * 8);
        acc0 = __builtin_amdgcn_mfma_f32_32x32x16_bf16(cw0[i], b0, acc0, 0, 0, 0);
        acc1 = __builtin_amdgcn_mfma_f32_32x32x16_bf16(cw1[i], b0, acc1, 0, 0, 0);
      }
      if (c < 2) {
#pragma unroll
        for (int i = 0; i < 8; i++) { cw0[i] = nw0[i]; cw1[i] = nw1[i]; }
      }
    }
    int tile = b * 128 + tt;
    f32x16 am[2] = {acc0, acc1};
#pragma unroll
    for (int mt = 0; mt < 2; mt++)
#pragma unroll
      for (int rg = 0; rg < 4; rg++) {
        u16x4 o;
#pragma unroll
        for (int i = 0; i < 4; i++) o[i] = f2bf(am[mt][rg * 4 + i]);
        *reinterpret_cast<u16x4*>(Ysel + tile * 2048 + (mt * 2 + (rg >> 1)) * 512
                                  + (((rg & 1) << 5) + l31) * 8 + 4 * h8) = o;
      }
  } else {
    int vw = wid - 2;
    const unsigned short* Wb = ws_r + OWVB + vw * 2 * 12288 + lane * 8;
    f32x16 acc0 = fz16, acc1 = fz16;
    bf16x8 cw0[8], cw1[8], nw0[8], nw1[8];
#pragma unroll
    for (int i = 0; i < 8; i++) {
      cw0[i] = ldb8(Wb + i * 512);
      cw1[i] = ldb8(Wb + 12288 + i * 512);
    }
    asm volatile("" ::: "memory");
#pragma unroll
    for (int c = 0; c < 3; c++) {
      if (c < 2) {
#pragma unroll
        for (int i = 0; i < 8; i++) {
          nw0[i] = ldb8(Wb + (c + 1) * 4096 + i * 512);
          nw1[i] = ldb8(Wb + 12288 + (c + 1) * 4096 + i * 512);
        }
        asm volatile("" ::: "memory");
      }
#pragma unroll
      for (int i = 0; i < 8; i++) {
        bf16x8 a0 = ldb8(xlds + (c * 8 + i) * 512 + lane * 8);
        acc0 = __builtin_amdgcn_mfma_f32_32x32x16_bf16(a0, cw0[i], acc0, 0, 0, 0);
        acc1 = __builtin_amdgcn_mfma_f32_32x32x16_bf16(a0, cw1[i], acc1, 0, 0, 0);
      }
      if (c < 2) {
#pragma unroll
        for (int i = 0; i < 8; i++) { cw0[i] = nw0[i]; cw1[i] = nw1[i]; }
      }
    }
    int k128 = tt >> 2;                       // key-block within batch
    int ks0 = (tb2 & 3) * 2;                  // kseg base within 128-key tile
    f32x16 ad[2] = {acc0, acc1};
#pragma unroll
    for (int dt = 0; dt < 2; dt++) {
      int dti = vw * 2 + dt;
      unsigned short* vbase = Vt + ((b * 12 + dti) * 32 + k128) * 4096;
#pragma unroll
      for (int rg = 0; rg < 4; rg++) {
        u16x4 o;
#pragma unroll
        for (int i = 0; i < 4; i++) o[i] = f2bf(ad[dt][rg * 4 + i]);
        int kseg = ks0 + (rg >> 1);
        *reinterpret_cast<u16x4*>(vbase + kseg * 512
                                  + (((rg & 1) << 5) + l31) * 8 + 4 * h8) = o;
      }
    }
  }
}

// ---------------- 3. Flash attention: lgkm-only barrier + 1-iter load prefetch -----
// b = (blk&7)>>1: each XCD works one batch. Per visit: QK(kf, prefetched) ->
// issue kf(kb+1) -> exp/pack/Pwrite -> lgkmcnt(0)+s_barrier (V loads stay in
// flight!) -> Pread -> PV(vf, prefetched) -> issue vf(kb+1).
__global__ __launch_bounds__(256, 2) void flash_attn(
    const unsigned short* __restrict__ Yk, const unsigned short* __restrict__ Yq,
    const unsigned short* __restrict__ Vt, float* __restrict__ out) {
  __shared__ __align__(16) unsigned short pbuf[2][8192];  // [kseg(8)][lane(64)][j(8)]
  __shared__ float lred[4][32];
  int blk = blockIdx.x;
  int xcd = blk & 7;
  int b = xcd >> 1, half = xcd & 1;
  int n = blk >> 3;
  int st = (n < 32) ? (127 - 2 * n - half) : (2 * (n - 32) + half);
  int wid = threadIdx.x >> 6, lane = threadIdx.x & 63;
  int l31 = lane & 31, h8 = lane >> 5;
  const f32x16 fz16 = {};
  const unsigned short* qbase = Yq + (b * 128 + st) * 2048 + lane * 8;
  bf16x8 qf[4];
#pragma unroll
  for (int ks = 0; ks < 4; ks++) qf[ks] = ldb8(qbase + ks * 512);
  f32x16 acc[3];
  acc[0] = fz16; acc[1] = fz16; acc[2] = fz16;
  float psum = 0.f;
  int n128 = (st >> 2) + 1;
  int qrow = st * 32 + l31;
  const unsigned short* kbase = Yk + (b * 128 + wid) * 2048 + lane * 8;
  const unsigned short* vbase = Vt + ((b * 12 + wid * 3) * 32) * 4096 + lane * 8;
  // prologue: K(0), V(0) in flight
  bf16x8 kf[4];
#pragma unroll
  for (int ks = 0; ks < 4; ks++) kf[ks] = ldb8(kbase + ks * 512);
  bf16x8 vf0[8], vf1[8], vf2[8];
#pragma unroll
  for (int g = 0; g < 8; g++) vf0[g] = ldb8(vbase + g * 512);
#pragma unroll
  for (int g = 0; g < 8; g++) vf1[g] = ldb8(vbase + 32 * 4096 + g * 512);
#pragma unroll
  for (int g = 0; g < 8; g++) vf2[g] = ldb8(vbase + 64 * 4096 + g * 512);
  asm volatile("" ::: "memory");
#pragma unroll 1
  for (int kb = 0; kb < n128; kb++) {
    f32x16 sacc = fz16;
#pragma unroll
    for (int ks = 0; ks < 4; ks++)
      sacc = __builtin_amdgcn_mfma_f32_32x32x16_bf16(kf[ks], qf[ks], sacc, 0, 0, 0);
    // prefetch K(kb+1) now: lands during exp/barrier/PV (~900 cy)
    int kn = (kb + 1 < n128) ? kb + 1 : kb;
    const unsigned short* ktn = kbase + kn * 8192;
    bf16x8 kfn[4];
#pragma unroll
    for (int ks = 0; ks < 4; ks++) kfn[ks] = ldb8(ktn + ks * 512);
    asm volatile("" ::: "memory");
    int kg0 = kb * 128 + wid * 32 + 4 * h8;
    unsigned short* pw = pbuf[kb & 1];
#pragma unroll
    for (int rg = 0; rg < 4; rg++) {
      u16x4 o;
#pragma unroll
      for (int i = 0; i < 4; i++) {
        int key = kg0 + rg * 8 + i;
        float pv = (key > qrow) ? 0.f : exp2f(sacc[rg * 4 + i] * C_EXP);
        psum += pv;
        o[i] = f2bf(pv);
      }
      int g = wid * 2 + (rg >> 1);
      *reinterpret_cast<u16x4*>(pw + g * 512 + ((rg & 1) * 32 + l31) * 8 + 4 * h8) = o;
    }
    // lgkm-only barrier: commits P writes (and drains last iter's P reads) but
    // leaves the prefetched global loads in flight — no vmcnt(0) drain.
    asm volatile("s_waitcnt lgkmcnt(0)" ::: "memory");
    __builtin_amdgcn_s_barrier();
    asm volatile("" ::: "memory");
    bf16x8 pf[8];
#pragma unroll
    for (int g = 0; g < 8; g++) pf[g] = ldb8(pw + g * 512 + lane * 8);
#pragma unroll
    for (int g = 0; g < 8; g++) {
      acc[0] = __builtin_amdgcn_mfma_f32_32x32x16_bf16(vf0[g], pf[g], acc[0], 0, 0, 0);
      acc[1] = __builtin_amdgcn_mfma_f32_32x32x16_bf16(vf1[g], pf[g], acc[1], 0, 0, 0);
      acc[2] = __builtin_amdgcn_mfma_f32_32x32x16_bf16(vf2[g], pf[g], acc[2], 0, 0, 0);
    }
    // prefetch V(kb+1): lands during next QK/exp/barrier (~700 cy)
    const unsigned short* vtn = vbase + kn * 4096;
#pragma unroll
    for (int g = 0; g < 8; g++) vf0[g] = ldb8(vtn + g * 512);
#pragma unroll
    for (int g = 0; g < 8; g++) vf1[g] = ldb8(vtn + 32 * 4096 + g * 512);
#pragma unroll
    for (int g = 0; g < 8; g++) vf2[g] = ldb8(vtn + 64 * 4096 + g * 512);
    asm volatile("" ::: "memory");
#pragma unroll
    for (int ks = 0; ks < 4; ks++) kf[ks] = kfn[ks];
  }
  psum += __shfl_xor(psum, 32);
  if (h8 == 0) lred[wid][l31] = psum;
  __syncthreads();
  float lt = lred[0][l31] + lred[1][l31] + lred[2][l31] + lred[3][l31];
  float inv = 1.0f / lt;
  float* ob = out + (b * TT + st * 32 + l31) * DD + wid * 96;
#pragma unroll
  for (int dt = 0; dt < 3; dt++)
#pragma unroll
    for (int rg = 0; rg < 4; rg++) {
      float4 o4;
      o4.x = acc[dt][rg * 4 + 0] * inv; o4.y = acc[dt][rg * 4 + 1] * inv;
      o4.z = acc[dt][rg * 4 + 2] * inv; o4.w = acc[dt][rg * 4 + 3] * inv;
      *reinterpret_cast<float4*>(ob + dt * 32 + rg * 8 + h8 * 4) = o4;
    }
}

extern "C" void kernel_launch(void* const* d_in, const int* in_sizes, int n_in,
                              void* d_out, int out_size, void* d_ws, size_t ws_size,
                              hipStream_t stream) {
  const float* x  = (const float*)d_in[0];
  const float* Wk = (const float*)d_in[1];
  const float* Wq = (const float*)d_in[2];
  const float* Wv = (const float*)d_in[3];
  unsigned short* ws = (unsigned short*)d_ws;
  unsigned short* Yk = ws + OYK;
  unsigned short* Yq = ws + OYQ;
  unsigned short* Vt = ws + OVT;

  convert_w<<<192, 256, 0, stream>>>(Wk, Wq, Wv, ws);
  proj_fused<<<512, 512, 0, stream>>>(x, ws, Yk, Yq, Vt);
  flash_attn<<<512, 256, 0, stream>>>(Yk, Yq, Vt, (float*)d_out);
}